// Round 3
// baseline (157.621 us; speedup 1.0000x reference)
//
#include <hip/hip_runtime.h>
#include <stdint.h>

// KANLinear fused kernel v3 for MI355X (gfx950).
// out = x @ bw + scaling * einsum('bik,iok->bo', basis(x), sw)
// One bf16 MFMA GEMM: K = 256 i-slabs x 80 (66 basis + base term at k=66 + zero pad).
// v3 changes vs v2 (which was occupancy-capped: grid 256 = 1 blk/CU, unified regs
// ~172/wave from breg[2][10]+acc[4], MfmaUtil 21.5%, Occ 20.4%):
//   - BM 128->64, grid 512 (2 blocks/CU resident): one block's MFMA overlaps the
//     other's BASIS/barrier phase
//   - wave tile 64x32 (8 N-col waves, full-M): breg[2][5] (40 v) + acc[2] (32 a)
//     ~= 110 unified regs -> 4 waves/EU; __launch_bounds__(512,4) enforces
//   - BASIS: 8 threads/row, 16-iter unroll (was 24) -> 33% less VALU per wave-slab
//   - LDS 22.5 KB/block (45 KB/CU at 2 blocks)
// Epilogue: per-split partial tiles in d_ws + reduce kernel (no atomics); atomic
// fallback if ws is small.
// (Rounds 1-2: container-level infra failures, no kernel diagnostics; source
//  audited clean twice — resubmitting unchanged to preserve the A/B vs v2.)

#define IN_F 256
#define OUT_F 256
#define NB 66
#define KP 80        // padded K per i-slab: 66 basis + base at k=66 + zeros, = 5 x K16
#define APAD 88      // A LDS row stride in ushorts
#define KSPLIT 8
#define SLABS 32     // IN_F / KSPLIT
#define BM 64
#define NTHREADS 512
#define GRID_MAIN 512   // (4096/BM) * KSPLIT

typedef __attribute__((ext_vector_type(8))) short bf16x8;
typedef __attribute__((ext_vector_type(16))) float f32x16;

__device__ __forceinline__ unsigned int f2bf(float f) {
  unsigned int u = __float_as_uint(f);
  u += 0x7FFFu + ((u >> 16) & 1u);   // round-to-nearest-even
  return u >> 16;
}

// ---- scaling partial: block b sums i in [b*32, b*32+32); pack kernel finishes the mean ----
__global__ void kan_scale8(const float* __restrict__ sca, float* __restrict__ wsp) {
  const int o = threadIdx.x, b = blockIdx.x;
  float s = 0.0f;
  #pragma unroll
  for (int j = 0; j < 32; j++) {
    const int i = b * 32 + j;
    s += fmaxf(sca[(size_t)i * OUT_F + o], 1e-7f);
  }
  wsp[b * OUT_F + o] = s;
}

// ---- pack W' -> wp2, layout (i*10 + g)*256 + o of 8-bf16 chunks, g = kk*2+half ----
// k<66 = sw*scaling[o]; k=66 = bw; 67..79 = 0. Coalesced uint4 stores.
__global__ void kan_pack(const float* __restrict__ sw, const float* __restrict__ bw,
                         const float* __restrict__ wsp, unsigned short* __restrict__ wp2) {
  const int i = blockIdx.x, o = threadIdx.x;
  float sc = 0.0f;
  #pragma unroll
  for (int b = 0; b < 8; b++) sc += wsp[b * OUT_F + o];
  sc *= (1.0f / 256.0f);
  const float2* src = (const float2*)(sw + ((size_t)i * OUT_F + o) * NB);
  float v[80];
  #pragma unroll
  for (int j = 0; j < 33; j++) {
    float2 t2 = src[j];
    v[2 * j] = t2.x * sc;
    v[2 * j + 1] = t2.y * sc;
  }
  v[66] = bw[(size_t)i * OUT_F + o];
  #pragma unroll
  for (int k = 67; k < 80; k++) v[k] = 0.0f;
  uint4* dst = (uint4*)wp2;
  #pragma unroll
  for (int g = 0; g < 10; g++) {
    uint4 u;
    unsigned int* up = (unsigned int*)&u;
    #pragma unroll
    for (int h = 0; h < 4; h++)
      up[h] = f2bf(v[g * 8 + 2 * h]) | (f2bf(v[g * 8 + 2 * h + 1]) << 16);
    dst[((size_t)i * 10 + g) * OUT_F + o] = u;
  }
}

// ---- main fused GEMM ----
__global__ __launch_bounds__(NTHREADS, 4) void kan_main(
    const float* __restrict__ x, const unsigned short* __restrict__ wp2,
    float* __restrict__ dst, int atomic_mode) {
  __shared__ unsigned short A[2][BM * APAD];   // 22528 B

  const int t = threadIdx.x;
  const int lane = t & 63;
  const int w = t >> 6;            // 0..7: wave N-col (32 cols each)
  const int ml = lane & 31;
  const int half = lane >> 5;
  const int mblk = (int)blockIdx.x >> 3;
  const int kidx = (int)blockIdx.x & 7;   // XCD-affine split-K index
  const int b0 = mblk * BM;
  const int ibase = kidx * SLABS;

  // basis thread mapping: row rb = t>>3, 8 threads per row, 16B-aligned spans
  // span table (ushort units): q: 0->[0,16) 1->[16,24) 2->[24,32) 3->[32,40)
  //                               4->[40,56) 5->[56,64) 6->[64,72) 7->[72,80)
  const int rb = t >> 3;           // 0..63
  const int q = t & 7;
  const int ks = (q + (q > 0) + (q > 4)) * 8;
  const int len = ((q & 3) == 0) ? 16 : 8;   // q==0 or q==4 get 16
  const int nchunk = len >> 3;

  const float* xrow = x + (size_t)(b0 + rb) * IN_F;
  const int boff = (w * 32 + ml) * 8;   // ushort offset of this lane's B row chunk

  bf16x8 breg[2][5];
  f32x16 acc[2] = {f32x16{}, f32x16{}};

#define LOADB(P, ISLAB)                                                        \
  {                                                                            \
    const unsigned short* bp =                                                 \
        wp2 + (size_t)(ISLAB) * (OUT_F * KP) + half * 2048 + boff;             \
    _Pragma("unroll") for (int kk = 0; kk < 5; kk++) {                         \
      breg[P][kk] = *(const bf16x8*)(bp + kk * 4096);                          \
    }                                                                          \
  }

#define BASIS(BUFSEL, XVAL)                                                    \
  {                                                                            \
    const float xr_ = (XVAL);                                                  \
    const float xc_ = fminf(fmaxf(xr_, -1.0f), 1.0f);                          \
    const float xs_ = (xc_ + 1.0f) * (63.0f / (2.0f + 1e-7f));                 \
    const float tl_ = xs_ - fminf(floorf(xs_), 61.0f);                         \
    float e_[16];                                                              \
    float s_ = 0.0f;                                                           \
    _Pragma("unroll") for (int j = 0; j < 16; j++) {                           \
      const int k = ks + j;                                                    \
      const float d_ = tl_ - (float)k * (1.0f / 65.0f);                        \
      float ee = __expf(-2178.0f * d_ * d_);                                   \
      ee = (j < len && k < 66) ? ee : 0.0f;                                    \
      e_[j] = ee;                                                              \
      s_ += ee;                                                                \
    }                                                                          \
    s_ += __shfl_xor(s_, 1);                                                   \
    s_ += __shfl_xor(s_, 2);                                                   \
    s_ += __shfl_xor(s_, 4);                                                   \
    const float r_ = __fdividef(1.0f, s_ + 1e-7f);                             \
    unsigned short* Ar = &A[BUFSEL][rb * APAD + ks];                           \
    _Pragma("unroll") for (int c = 0; c < 2; c++) {                            \
      if (c < nchunk) {                                                        \
        uint4 u;                                                               \
        unsigned int* up = (unsigned int*)&u;                                  \
        _Pragma("unroll") for (int h = 0; h < 4; h++) {                        \
          const int k0 = ks + c * 8 + h * 2;                                   \
          float f0 = e_[c * 8 + h * 2] * r_;                                   \
          float f1 = e_[c * 8 + h * 2 + 1] * r_;                               \
          f0 = (k0 == 66) ? xr_ : f0;                                          \
          f1 = (k0 + 1 == 66) ? xr_ : f1;                                      \
          up[h] = f2bf(f0) | (f2bf(f1) << 16);                                 \
        }                                                                      \
        *(uint4*)(Ar + c * 8) = u;                                             \
      }                                                                        \
    }                                                                          \
  }

#define MFMA_SLAB(CUR, P)                                                      \
  {                                                                            \
    const unsigned short* Ac = &A[CUR][0];                                     \
    _Pragma("unroll") for (int kk = 0; kk < 5; kk++) {                         \
      const int ko = kk * 16 + half * 8;                                       \
      bf16x8 a0 = *(const bf16x8*)(Ac + ml * APAD + ko);                       \
      bf16x8 a1 = *(const bf16x8*)(Ac + (32 + ml) * APAD + ko);                \
      acc[0] = __builtin_amdgcn_mfma_f32_32x32x16_bf16(a0, breg[P][kk], acc[0], 0, 0, 0); \
      acc[1] = __builtin_amdgcn_mfma_f32_32x32x16_bf16(a1, breg[P][kk], acc[1], 0, 0, 0); \
    }                                                                          \
  }

  // ---- prologue: slab 0 basis + B regs ----
  BASIS(0, xrow[ibase]);
  LOADB(0, ibase);
  float xn = xrow[ibase + 1];
  __syncthreads();

#define STEP(II, P)                                                            \
  {                                                                            \
    if ((II) + 1 < SLABS) LOADB(1 - (P), ibase + (II) + 1);                    \
    MFMA_SLAB((II) & 1, P);                                                    \
    const float xc2 = xn;                                                      \
    if ((II) + 2 < SLABS) xn = xrow[ibase + (II) + 2];                         \
    if ((II) + 1 < SLABS) BASIS(((II) + 1) & 1, xc2);                          \
    __syncthreads();                                                           \
  }

  for (int ii = 0; ii < SLABS; ii += 2) {
    STEP(ii, 0);
    STEP(ii + 1, 1);
  }

  // ---- epilogue: C/D layout col=lane&31, row=(r&3)+8*(r>>2)+4*(lane>>5) ----
  const int colb = w * 32 + ml;
  if (atomic_mode) {
    #pragma unroll
    for (int mb = 0; mb < 2; mb++) {
      #pragma unroll
      for (int r = 0; r < 16; r++) {
        const int row = b0 + mb * 32 + (r & 3) + 8 * (r >> 2) + 4 * half;
        atomicAdd(&dst[(size_t)row * OUT_F + colb], acc[mb][r]);
      }
    }
  } else {
    float* pd = dst + (size_t)kidx * ((size_t)4096 * OUT_F);
    #pragma unroll
    for (int mb = 0; mb < 2; mb++) {
      #pragma unroll
      for (int r = 0; r < 16; r++) {
        const int row = b0 + mb * 32 + (r & 3) + 8 * (r >> 2) + 4 * half;
        pd[(size_t)row * OUT_F + colb] = acc[mb][r];
      }
    }
  }
}

// ---- split-K reduce: out = sum of 8 partial tiles ----
__global__ void kan_reduce(const float* __restrict__ part, float* __restrict__ out) {
  const size_t j = ((size_t)blockIdx.x * 256 + threadIdx.x) * 4;
  float4 a = *(const float4*)(part + j);
  #pragma unroll
  for (int s = 1; s < 8; s++) {
    float4 b = *(const float4*)(part + (size_t)s * 1048576 + j);
    a.x += b.x; a.y += b.y; a.z += b.z; a.w += b.w;
  }
  *(float4*)(out + j) = a;
}

// ---- naive fallback (only if d_ws is too small): correct, slow ----
__global__ void kan_naive(const float* __restrict__ x, const float* __restrict__ bw,
                          const float* __restrict__ sw, const float* __restrict__ sca,
                          float* __restrict__ out) {
  const int o = threadIdx.x;
  const int b = blockIdx.x;
  float accb = 0.0f, accs = 0.0f, scl = 0.0f;
  for (int i = 0; i < IN_F; i++) {
    const float xraw = x[(size_t)b * IN_F + i];
    accb += xraw * bw[(size_t)i * OUT_F + o];
    scl += fmaxf(sca[(size_t)i * OUT_F + o], 1e-7f);
    const float xc = fminf(fmaxf(xraw, -1.0f), 1.0f);
    const float xs = (xc + 1.0f) * (63.0f / (2.0f + 1e-7f));
    const float tl = xs - fminf(floorf(xs), 61.0f);
    const int kc = (int)(tl * 65.0f + 0.5f);
    const int k0 = max(0, min(kc - 8, 50));
    float e[16]; float s = 0.0f;
    #pragma unroll
    for (int j = 0; j < 16; j++) {
      float d = tl - (float)(k0 + j) * (1.0f / 65.0f);
      e[j] = __expf(-2178.0f * d * d);
      s += e[j];
    }
    const float r = __fdividef(1.0f, s + 1e-7f);
    const float* wrow = sw + ((size_t)i * OUT_F + o) * NB + k0;
    float dot = 0.0f;
    #pragma unroll
    for (int j = 0; j < 16; j++) dot += e[j] * wrow[j];
    accs += dot * r;
  }
  out[(size_t)b * OUT_F + o] = accb + accs * (scl * (1.0f / 256.0f));
}

extern "C" void kernel_launch(void* const* d_in, const int* in_sizes, int n_in,
                              void* d_out, int out_size, void* d_ws, size_t ws_size,
                              hipStream_t stream) {
  const float* x   = (const float*)d_in[0];
  const float* bw  = (const float*)d_in[1];
  const float* sw  = (const float*)d_in[2];
  const float* sca = (const float*)d_in[3];
  float* out = (float*)d_out;

  const size_t WP2_BYTES  = (size_t)IN_F * OUT_F * KP * 2;          // 10485760
  const size_t WP_OFF     = 8192;                                   // after wsp[8][256]
  const size_t PART_OFF   = WP_OFF + WP2_BYTES;                     // 10493952
  const size_t PART_BYTES = (size_t)KSPLIT * 4096 * OUT_F * 4;      // 33554432

  if (ws_size >= PART_OFF + PART_BYTES) {
    float* wsp = (float*)d_ws;
    unsigned short* wp2 = (unsigned short*)((char*)d_ws + WP_OFF);
    float* part = (float*)((char*)d_ws + PART_OFF);
    kan_scale8<<<8, 256, 0, stream>>>(sca, wsp);
    kan_pack<<<256, 256, 0, stream>>>(sw, bw, wsp, wp2);
    kan_main<<<GRID_MAIN, NTHREADS, 0, stream>>>(x, wp2, part, 0);
    kan_reduce<<<1024, 256, 0, stream>>>(part, out);
  } else if (ws_size >= PART_OFF) {
    float* wsp = (float*)d_ws;
    unsigned short* wp2 = (unsigned short*)((char*)d_ws + WP_OFF);
    hipMemsetAsync(d_out, 0, (size_t)out_size * sizeof(float), stream);
    kan_scale8<<<8, 256, 0, stream>>>(sca, wsp);
    kan_pack<<<256, 256, 0, stream>>>(sw, bw, wsp, wp2);
    kan_main<<<GRID_MAIN, NTHREADS, 0, stream>>>(x, wp2, out, 1);
  } else {
    kan_naive<<<4096, 256, 0, stream>>>(x, bw, sw, sca, out);
  }
}